// Round 10
// baseline (336.682 us; speedup 1.0000x reference)
//
#include <hip/hip_runtime.h>
#include <hip/hip_bf16.h>

typedef __attribute__((ext_vector_type(4))) float f32x4;
typedef __attribute__((ext_vector_type(8))) short short8;
typedef __attribute__((ext_vector_type(4))) unsigned int u32x4;

__device__ __forceinline__ unsigned short f2bf(float f) {
  union { float f; unsigned int u; } v; v.f = f;
  unsigned int r = (v.u + 0x7fffu + ((v.u >> 16) & 1u)) >> 16;
  return (unsigned short)r;
}
__device__ __forceinline__ unsigned short f2bf_fast(float f) {
  __hip_bfloat16 h = __float2bfloat16(f);
  return __builtin_bit_cast(unsigned short, h);
}
__device__ __forceinline__ float bf2f(unsigned short h) {
  union { unsigned int u; float f; } v; v.u = ((unsigned int)h) << 16;
  return v.f;
}
__device__ __forceinline__ unsigned int cvt_pk_bf16(float lo, float hi) {
  unsigned int r;
  asm("v_cvt_pk_bf16_f32 %0, %1, %2" : "=v"(r) : "v"(lo), "v"(hi));
  return r;
}

__device__ __forceinline__ void gload_lds16(const void* g, void* l) {
  __builtin_amdgcn_global_load_lds((const __attribute__((address_space(1))) void*)g,
                                   (__attribute__((address_space(3))) void*)l,
                                   16, 0, 0);
}

template <int N>
__device__ __forceinline__ void vmwait() {
  asm volatile("s_waitcnt vmcnt(%0)" :: "n"(N) : "memory");
}

// ---------------- fused f32 -> bf16 convert for all 5 inputs ----------------
__global__ __launch_bounds__(256) void cvt_all(
    const float* __restrict__ hid, const float* __restrict__ wq,
    const float* __restrict__ wk, const float* __restrict__ wv,
    const float* __restrict__ wo, unsigned short* __restrict__ out) {
  const size_t E0 = 8388608, E1 = 25165824, E2 = 29360128, E3 = 33554432, E4 = 50331648;
  size_t stride = (size_t)gridDim.x * blockDim.x;
  for (size_t i = (size_t)blockIdx.x * blockDim.x + threadIdx.x; i * 4 < E4; i += stride) {
    size_t i4 = i * 4;
    const float* src; size_t rel;
    if (i4 < E0)      { src = hid; rel = i4; }
    else if (i4 < E1) { src = wq;  rel = i4 - E0; }
    else if (i4 < E2) { src = wk;  rel = i4 - E1; }
    else if (i4 < E3) { src = wv;  rel = i4 - E2; }
    else              { src = wo;  rel = i4 - E3; }
    float4 v = *(const float4*)(src + rel);
    ushort4 o;
    o.x = f2bf(v.x); o.y = f2bf(v.y); o.z = f2bf(v.z); o.w = f2bf(v.w);
    *(ushort4*)(out + i4) = o;
  }
}

// ---------------- pipelined GEMM: C[M][N] = A[M][K] * B[N][K]^T ----------------
// 256 threads / 4 waves (2x2), BK=32, DEPTH-deep LDS ring, counted vmcnt
// (never 0 until drain), one barrier per K-tile, stage issued DEPTH-1 ahead.
// 2 blocks/CU (LDS <= 80KB): independent blocks desync so one block's MFMA
// covers the other's barrier/load stalls (round-10 lever; round-9 had 1
// lockstep block/CU -> SIMD idle at every barrier).
// Grid (N/BN, M/BM) = 512 blocks. With grid.x=32, same-B-panel blocks differ
// by 32 in linear id (== 0 mod 8 XCDs) -> B panels are XCD-L2-local.
template <int BM, int BN, int DEPTH, bool BF16_OUT>
__global__ __launch_bounds__(256, 2) void gemm_p(
    const unsigned short* __restrict__ A,
    const unsigned short* __restrict__ B,
    void* __restrict__ Cout, int M, int N, int K) {
  constexpr int BK = 32;
  constexpr int MFRAG = BM / 32;                 // per-wave m-frags (2 wave-rows)
  constexpr int NFRAG = BN / 32;                 // per-wave n-frags (2 wave-cols)
  constexpr int ASHORTS = BM * BK;
  constexpr int BSHORTS = BN * BK;
  constexpr int BUFSH = ASHORTS + BSHORTS;
  constexpr int ALOADS = BM / 64;                // 64 rows per 256-thread load inst
  constexpr int BLOADS = BN / 64;
  constexpr int LPT = ALOADS + BLOADS;
  __shared__ unsigned short lds[DEPTH * BUFSH];

  const int tid = threadIdx.x;
  const int wave = tid >> 6, lane = tid & 63;
  const int l15 = lane & 15, l4 = lane >> 4;
  const int row0 = blockIdx.y * BM, col0 = blockIdx.x * BN;
  const int mrow0 = (wave >> 1) * (BM / 2);
  const int ncol0 = (wave & 1) * (BN / 2);
  const int NT = K >> 5;
  const int srow = tid >> 2;          // 0..63 (stage row within 64-row chunk)
  const int scel = (tid & 3) * 8;     // stage col element (linear)

  f32x4 zv = {0.f, 0.f, 0.f, 0.f};
  f32x4 acc[MFRAG][NFRAG];
#pragma unroll
  for (int m = 0; m < MFRAG; ++m)
#pragma unroll
    for (int n = 0; n < NFRAG; ++n) acc[m][n] = zv;

  auto stage = [&](int t) {
    unsigned short* buf = &lds[(t % DEPTH) * BUFSH];
    const int k0 = t * BK;
#pragma unroll
    for (int i = 0; i < ALOADS; ++i)
      gload_lds16(A + (size_t)(row0 + i * 64 + srow) * K + k0 + scel,
                  buf + i * 2048 + tid * 8);
#pragma unroll
    for (int i = 0; i < BLOADS; ++i)
      gload_lds16(B + (size_t)(col0 + i * 64 + srow) * K + k0 + scel,
                  buf + ASHORTS + i * 2048 + tid * 8);
  };

#pragma unroll
  for (int i = 0; i < DEPTH - 1; ++i) stage(i);

  for (int t = 0; t < NT; ++t) {
    const int rem = NT - 1 - t;
    if (rem >= 2)      vmwait<2 * LPT>();
    else if (rem == 1) vmwait<LPT>();
    else               vmwait<0>();
    __builtin_amdgcn_sched_barrier(0);
    __builtin_amdgcn_s_barrier();     // everyone's tile-t loads in; everyone done reading t-1
    __builtin_amdgcn_sched_barrier(0);
    if (t + DEPTH - 1 < NT) stage(t + DEPTH - 1);  // ring slot provably idle

    const unsigned short* Abuf = &lds[(t % DEPTH) * BUFSH];
    const unsigned short* Bbuf = Abuf + ASHORTS;
    short8 bfr[NFRAG], afr[MFRAG];
#pragma unroll
    for (int n = 0; n < NFRAG; ++n)
      bfr[n] = *(const short8*)&Bbuf[(ncol0 + n * 16 + l15) * BK + l4 * 8];
#pragma unroll
    for (int m = 0; m < MFRAG; ++m)
      afr[m] = *(const short8*)&Abuf[(mrow0 + m * 16 + l15) * BK + l4 * 8];
    __builtin_amdgcn_s_setprio(1);
#pragma unroll
    for (int m = 0; m < MFRAG; ++m)
#pragma unroll
      for (int n = 0; n < NFRAG; ++n)
        acc[m][n] = __builtin_amdgcn_mfma_f32_16x16x32_bf16(afr[m], bfr[n], acc[m][n], 0, 0, 0);
    __builtin_amdgcn_s_setprio(0);
    __builtin_amdgcn_sched_barrier(0);
  }

#pragma unroll
  for (int m = 0; m < MFRAG; ++m)
#pragma unroll
    for (int n = 0; n < NFRAG; ++n)
#pragma unroll
      for (int j = 0; j < 4; ++j) {
        int r = row0 + mrow0 + m * 16 + l4 * 4 + j;
        int cc = col0 + ncol0 + n * 16 + l15;
        if constexpr (BF16_OUT)
          ((unsigned short*)Cout)[(size_t)r * N + cc] = f2bf(acc[m][n][j]);
        else
          ((float*)Cout)[(size_t)r * N + cc] = acc[m][n][j];
      }
}

// ---------------- RoPE (in-place on fused QKV [2048][6144]) ----------------
__global__ __launch_bounds__(256) void rope_k(unsigned short* __restrict__ QKV) {
  int idx = blockIdx.x * blockDim.x + threadIdx.x;
  if (idx >= 2048 * 40 * 64) return;
  int j = idx & 63;
  int rest = idx >> 6;
  int slot = rest % 40;
  int s = rest / 40;
  int doff = (slot < 32) ? slot * 128 : 4096 + (slot - 32) * 128;
  unsigned short* p = QKV + (size_t)s * 6144 + doff;
  float inv = exp2f((float)j * -0.20762050593046015f);
  float ang = (float)s * inv;
  float sn, cs;
  sincosf(ang, &sn, &cs);
  float x1 = bf2f(p[j]), x2 = bf2f(p[j + 64]);
  p[j]      = f2bf(x1 * cs - x2 * sn);
  p[j + 64] = f2bf(x2 * cs + x1 * sn);
}

// ---------------- causal GQA flash attention (swapped QK^T, in-register softmax) ----------------
// Lane owns q = l15 after S^T = mfma(K, Q): sacc[cb][j] = S[q=l15][kv = cb*16 + l4*4 + j].
__global__ __launch_bounds__(512, 4) void attn_k(
    const unsigned short* __restrict__ QKV,  // [2048][6144]
    unsigned short* __restrict__ O) {        // [2048][4096]
  __shared__ unsigned short Ks[2][64 * 128];
  __shared__ unsigned short Vs[2][64 * 128];

  const int tid = threadIdx.x;
  const int wave = tid >> 6, lane = tid & 63;
  const int l15 = lane & 15, l4 = lane >> 4;

  const int bid = blockIdx.x;
  const int qt16 = bid & 15;
  const int h = (bid >> 4) & 31;
  const int qt = (h < 16) ? (15 - qt16) : qt16;
  const int hkv = h >> 2;
  const int q0 = qt * 128;
  const int qrow = q0 + wave * 16 + l15;
  const float C2 = 0.12751744219938793f;  // log2(e)/sqrt(128)

  const unsigned short* Qp = QKV + h * 128;
  const unsigned short* Kp = QKV + 4096 + hkv * 128;
  const unsigned short* Vp = QKV + 5120 + hkv * 128;

  const int vpr = tid >> 4;
  const int vd8 = tid & 15;
  const int vg8 = vpr >> 2, vjj = 2 * (vpr & 3);
  const int vn = vd8 >> 1, vch = (vd8 & 1) * 8;

  short8 qf[4];
#pragma unroll
  for (int kc = 0; kc < 4; ++kc)
    qf[kc] = *(const short8*)(Qp + (size_t)qrow * 6144 + kc * 32 + l4 * 8);

  f32x4 zv = {0.f, 0.f, 0.f, 0.f};
  f32x4 oacc[8];
#pragma unroll
  for (int n = 0; n < 8; ++n) oacc[n] = zv;
  float mrow = -3.0e38f, lrow = 0.f;

  auto stageK = [&](int kvn, int b) {
#pragma unroll
    for (int i = 0; i < 2; ++i) {
      int c = wave * 2 + i;
      int row = c * 4 + l4;
      int colel = (l15 * 8) ^ ((row & 7) << 3);
      gload_lds16(Kp + (size_t)(kvn + row) * 6144 + colel, &Ks[b][c * 512]);
    }
  };
  auto loadV = [&](int kvn, short8& va, short8& vb) {
    va = *(const short8*)(Vp + (size_t)(kvn + 2 * vpr) * 6144 + vd8 * 8);
    vb = *(const short8*)(Vp + (size_t)(kvn + 2 * vpr + 1) * 6144 + vd8 * 8);
  };
  auto writeV = [&](int b, const short8& va, const short8& vb) {
#pragma unroll
    for (int i = 0; i < 8; ++i) {
      int c = vch + i;
      unsigned int pack = (unsigned int)(unsigned short)va[i] |
                          ((unsigned int)(unsigned short)vb[i] << 16);
      *(unsigned int*)&Vs[b][vg8 * 1024 + vn * 128 + ((c ^ vn) & 15) * 8 + vjj] = pack;
    }
  };

  {
    short8 va, vb;
    stageK(0, 0);
    loadV(0, va, vb);
    writeV(0, va, vb);
  }
  __syncthreads();

  const int nt = 2 * qt + 2;
  for (int t = 0; t < nt; ++t) {
    const int cur = t & 1, nxt = cur ^ 1;
    const int kv0 = t * 64;
    const bool has_next = (t + 1 < nt);
    short8 va, vb;
    if (has_next) {
      stageK(kv0 + 64, nxt);
      loadV(kv0 + 64, va, vb);
    }

    // ---- swapped QK^T ----
    f32x4 sacc[4];
#pragma unroll
    for (int cb = 0; cb < 4; ++cb) sacc[cb] = zv;
    __builtin_amdgcn_s_setprio(1);
#pragma unroll
    for (int cb = 0; cb < 4; ++cb) {
      int row = cb * 16 + l15;
      int sw = (row & 7) << 3;
#pragma unroll
      for (int kc = 0; kc < 4; ++kc) {
        short8 kf = *(const short8*)&Ks[cur][row * 128 + ((kc * 32 + l4 * 8) ^ sw)];
        sacc[cb] = __builtin_amdgcn_mfma_f32_16x16x32_bf16(kf, qf[kc], sacc[cb], 0, 0, 0);
      }
    }
    __builtin_amdgcn_s_setprio(0);

    // ---- mask ----
    if (kv0 + 63 > q0 + wave * 16) {
#pragma unroll
      for (int cb = 0; cb < 4; ++cb)
#pragma unroll
        for (int j = 0; j < 4; ++j) {
          int kvpos = kv0 + cb * 16 + l4 * 4 + j;
          if (kvpos > qrow) sacc[cb][j] = -3.0e38f;
        }
    }

    // ---- row max ----
    float pm = sacc[0][0];
#pragma unroll
    for (int cb = 0; cb < 4; ++cb)
#pragma unroll
      for (int j = 0; j < 4; ++j) pm = fmaxf(pm, sacc[cb][j]);
    pm = fmaxf(pm, __shfl_xor(pm, 16, 64));
    pm = fmaxf(pm, __shfl_xor(pm, 32, 64));

    // ---- defer-max rescale ----
    if (__any(pm > mrow + 64.0f)) {
      float mn = fmaxf(mrow, pm);
      float rs = exp2f((mrow - mn) * C2);
      mrow = mn;
      lrow *= rs;
      float rs0 = __shfl(rs, 4 * l4 + 0, 64);
      float rs1 = __shfl(rs, 4 * l4 + 1, 64);
      float rs2 = __shfl(rs, 4 * l4 + 2, 64);
      float rs3 = __shfl(rs, 4 * l4 + 3, 64);
#pragma unroll
      for (int n = 0; n < 8; ++n) {
        oacc[n][0] *= rs0; oacc[n][1] *= rs1;
        oacc[n][2] *= rs2; oacc[n][3] *= rs3;
      }
    }

    // ---- p = exp2, sum, pack ----
    unsigned int pack[8];
    float psum = 0.f;
#pragma unroll
    for (int cb = 0; cb < 4; ++cb) {
      float p0 = exp2f((sacc[cb][0] - mrow) * C2);
      float p1 = exp2f((sacc[cb][1] - mrow) * C2);
      float p2 = exp2f((sacc[cb][2] - mrow) * C2);
      float p3 = exp2f((sacc[cb][3] - mrow) * C2);
      psum += (p0 + p1) + (p2 + p3);
      pack[cb * 2 + 0] = cvt_pk_bf16(p0, p1);
      pack[cb * 2 + 1] = cvt_pk_bf16(p2, p3);
    }
    lrow += psum;

    // ---- PV ----
#pragma unroll
    for (int ks = 0; ks < 2; ++ks) {
      u32x4 pw;
#pragma unroll
      for (int w = 0; w < 4; ++w) {
        int sl = l15 + 16 * ((2 * l4 + (w >> 1)) & 3);
        int v0 = __shfl((int)pack[4 * ks + (w & 1)], sl, 64);
        int v1 = __shfl((int)pack[4 * ks + 2 + (w & 1)], sl, 64);
        pw[w] = (lane < 32) ? (unsigned int)v0 : (unsigned int)v1;
      }
      short8 pf = __builtin_bit_cast(short8, pw);
      __builtin_amdgcn_s_setprio(1);
#pragma unroll
      for (int n = 0; n < 8; ++n) {
        short8 vf = *(const short8*)&Vs[cur][(ks * 4 + l4) * 1024 + n * 128 + ((l15 ^ n) & 15) * 8];
        oacc[n] = __builtin_amdgcn_mfma_f32_16x16x32_bf16(pf, vf, oacc[n], 0, 0, 0);
      }
      __builtin_amdgcn_s_setprio(0);
    }

    if (has_next) writeV(nxt, va, vb);
    __syncthreads();
  }

  // ---- epilogue ----
  lrow += __shfl_xor(lrow, 16, 64);
  lrow += __shfl_xor(lrow, 32, 64);
  float linv = 1.0f / lrow;
  float li0 = __shfl(linv, 4 * l4 + 0, 64);
  float li1 = __shfl(linv, 4 * l4 + 1, 64);
  float li2 = __shfl(linv, 4 * l4 + 2, 64);
  float li3 = __shfl(linv, 4 * l4 + 3, 64);
#pragma unroll
  for (int n = 0; n < 8; ++n) {
    int r = q0 + wave * 16 + l4 * 4;
    size_t base = (size_t)r * 4096 + h * 128 + n * 16 + l15;
    O[base]          = f2bf_fast(oacc[n][0] * li0);
    O[base + 4096]   = f2bf_fast(oacc[n][1] * li1);
    O[base + 8192]   = f2bf_fast(oacc[n][2] * li2);
    O[base + 12288]  = f2bf_fast(oacc[n][3] * li3);
  }
}

extern "C" void kernel_launch(void* const* d_in, const int* in_sizes, int n_in,
                              void* d_out, int out_size, void* d_ws, size_t ws_size,
                              hipStream_t stream) {
  const float* hid = (const float*)d_in[0];
  const float* Wq  = (const float*)d_in[1];
  const float* Wk  = (const float*)d_in[2];
  const float* Wv  = (const float*)d_in[3];
  const float* Wo  = (const float*)d_in[4];

  char* ws = (char*)d_ws;
  size_t off = 0;
  unsigned short* hid_b = (unsigned short*)(ws + off); off += (size_t)2048 * 4096 * 2;
  unsigned short* Wq_b  = (unsigned short*)(ws + off); off += (size_t)4096 * 4096 * 2;
  unsigned short* Wk_b  = (unsigned short*)(ws + off); off += (size_t)1024 * 4096 * 2;
  unsigned short* Wv_b  = (unsigned short*)(ws + off); off += (size_t)1024 * 4096 * 2;
  unsigned short* Wo_b  = (unsigned short*)(ws + off); off += (size_t)4096 * 4096 * 2;
  unsigned short* QKV   = (unsigned short*)(ws + off); off += (size_t)2048 * 6144 * 2;
  unsigned short* Ob    = (unsigned short*)(ws + off); off += (size_t)2048 * 4096 * 2;
  (void)Wk_b; (void)Wv_b;

  cvt_all<<<4096, 256, 0, stream>>>(hid, Wq, Wk, Wv, Wo, hid_b);

  // fused QKV projection: B = [Wq; Wk; Wv] contiguous, N = 6144
  // grid 32x16 = 512 blocks = 2/CU (80KB LDS each)
  gemm_p<128, 192, 4, true><<<dim3(32, 16), 256, 0, stream>>>(hid_b, Wq_b, (void*)QKV, 2048, 6144, 4096);

  rope_k<<<20480, 256, 0, stream>>>(QKV);

  attn_k<<<512, 512, 0, stream>>>(QKV, Ob);

  // O projection: grid 32x16 = 512 blocks = 2/CU (64KB LDS each)
  gemm_p<128, 128, 4, false><<<dim3(32, 16), 256, 0, stream>>>(Ob, Wo_b, d_out, 2048, 4096, 4096);
}

// Round 11
// 317.214 us; speedup vs baseline: 1.0614x; 1.0614x over previous
//
#include <hip/hip_runtime.h>
#include <hip/hip_bf16.h>

typedef __attribute__((ext_vector_type(4))) float f32x4;
typedef __attribute__((ext_vector_type(8))) short short8;
typedef __attribute__((ext_vector_type(4))) unsigned int u32x4;

__device__ __forceinline__ unsigned short f2bf(float f) {
  union { float f; unsigned int u; } v; v.f = f;
  unsigned int r = (v.u + 0x7fffu + ((v.u >> 16) & 1u)) >> 16;
  return (unsigned short)r;
}
__device__ __forceinline__ unsigned short f2bf_fast(float f) {
  __hip_bfloat16 h = __float2bfloat16(f);
  return __builtin_bit_cast(unsigned short, h);
}
__device__ __forceinline__ float bf2f(unsigned short h) {
  union { unsigned int u; float f; } v; v.u = ((unsigned int)h) << 16;
  return v.f;
}
__device__ __forceinline__ unsigned int cvt_pk_bf16(float lo, float hi) {
  unsigned int r;
  asm("v_cvt_pk_bf16_f32 %0, %1, %2" : "=v"(r) : "v"(lo), "v"(hi));
  return r;
}

__device__ __forceinline__ void gload_lds16(const void* g, void* l) {
  __builtin_amdgcn_global_load_lds((const __attribute__((address_space(1))) void*)g,
                                   (__attribute__((address_space(3))) void*)l,
                                   16, 0, 0);
}

template <int N>
__device__ __forceinline__ void vmwait() {
  asm volatile("s_waitcnt vmcnt(%0)" :: "n"(N) : "memory");
}

// ---------------- fused f32 -> bf16 convert for all 5 inputs ----------------
__global__ __launch_bounds__(256) void cvt_all(
    const float* __restrict__ hid, const float* __restrict__ wq,
    const float* __restrict__ wk, const float* __restrict__ wv,
    const float* __restrict__ wo, unsigned short* __restrict__ out) {
  const size_t E0 = 8388608, E1 = 25165824, E2 = 29360128, E3 = 33554432, E4 = 50331648;
  size_t stride = (size_t)gridDim.x * blockDim.x;
  for (size_t i = (size_t)blockIdx.x * blockDim.x + threadIdx.x; i * 4 < E4; i += stride) {
    size_t i4 = i * 4;
    const float* src; size_t rel;
    if (i4 < E0)      { src = hid; rel = i4; }
    else if (i4 < E1) { src = wq;  rel = i4 - E0; }
    else if (i4 < E2) { src = wk;  rel = i4 - E1; }
    else if (i4 < E3) { src = wv;  rel = i4 - E2; }
    else              { src = wo;  rel = i4 - E3; }
    float4 v = *(const float4*)(src + rel);
    ushort4 o;
    o.x = f2bf(v.x); o.y = f2bf(v.y); o.z = f2bf(v.z); o.w = f2bf(v.w);
    *(ushort4*)(out + i4) = o;
  }
}

// ---------------- BK=64 double-buffered GEMM: C[M][N] = A[M][K] * B[N][K]^T ----
// 256 threads / 4 waves (2x2), BK=64, 2-deep LDS ring (prefetch distance = 1
// full iteration ~2200cy >> 900cy HBM latency), one barrier per K=64 (half the
// barrier/issue overhead of the BK=32 ring). 2 blocks/CU.
// LDS XOR-swizzle (mandatory at BK=64: 128B rows alias all 16 frag-rows to
// bank 0 -> 16-way conflict unswizzled): LDS 16B-slot s of row r holds global
// slot s^(r&7); staged via pre-swizzled per-lane GLOBAL source (linear LDS
// dest, rule: gload_lds writes base+lane*16 only); reads apply the same XOR.
// Read spread: per 16-lane group 8 distinct spans -> 2-way (free).
template <int BM, int BN, bool BF16_OUT>
__global__ __launch_bounds__(256, 2) void gemm_p2(
    const unsigned short* __restrict__ A,
    const unsigned short* __restrict__ B,
    void* __restrict__ Cout, int M, int N, int K) {
  constexpr int BK = 64;
  constexpr int MFRAG = BM / 32;                 // per-wave m-frags (2 wave-rows)
  constexpr int NFRAG = BN / 32;                 // per-wave n-frags (2 wave-cols)
  constexpr int ASH = BM * BK;
  constexpr int BSH = BN * BK;
  constexpr int BUF = ASH + BSH;
  constexpr int ALOADS = BM / 32;                // 32 rows per 256-thread load inst
  constexpr int BLOADS = BN / 32;
  __shared__ unsigned short lds[2 * BUF];

  const int tid = threadIdx.x;
  const int wave = tid >> 6, lane = tid & 63;
  const int l15 = lane & 15, l4 = lane >> 4;
  const int row0 = blockIdx.y * BM, col0 = blockIdx.x * BN;
  const int mrow0 = (wave >> 1) * (BM / 2);      // 0 or BM/2 (mult of 8)
  const int ncol0 = (wave & 1) * (BN / 2);       // 0 or BN/2 (mult of 8)
  const int NT = K >> 6;
  const int srow = tid >> 3;                     // 0..31 row within 32-row chunk
  const int scol = ((tid & 7) ^ (srow & 7)) * 8; // pre-swizzled global col (elems)

  f32x4 zv = {0.f, 0.f, 0.f, 0.f};
  f32x4 acc[MFRAG][NFRAG];
#pragma unroll
  for (int m = 0; m < MFRAG; ++m)
#pragma unroll
    for (int n = 0; n < NFRAG; ++n) acc[m][n] = zv;

  auto stage = [&](int t) {
    unsigned short* buf = &lds[(t & 1) * BUF];
    const int k0 = t * BK;
#pragma unroll
    for (int i = 0; i < ALOADS; ++i)
      gload_lds16(A + (size_t)(row0 + i * 32 + srow) * K + k0 + scol,
                  buf + i * 2048 + tid * 8);
#pragma unroll
    for (int i = 0; i < BLOADS; ++i)
      gload_lds16(B + (size_t)(col0 + i * 32 + srow) * K + k0 + scol,
                  buf + ASH + i * 2048 + tid * 8);
  };

  stage(0);

  for (int t = 0; t < NT; ++t) {
    // tile t's loads were issued one full iteration ago -> this wait is free,
    // and it is exactly the "tile t landed" condition for the double buffer.
    vmwait<0>();
    __builtin_amdgcn_sched_barrier(0);
    __builtin_amdgcn_s_barrier();   // all waves done reading buf[(t+1)&1] (iter t-1)
    __builtin_amdgcn_sched_barrier(0);
    if (t + 1 < NT) stage(t + 1);

    const unsigned short* Ab = &lds[(t & 1) * BUF];
    const unsigned short* Bb = Ab + ASH;
#pragma unroll
    for (int h = 0; h < 2; ++h) {               // k-half: k in [h*32, h*32+32)
      short8 afr[MFRAG], bfr[NFRAG];
#pragma unroll
      for (int m = 0; m < MFRAG; ++m) {
        int row = mrow0 + m * 16 + l15;         // row&7 == l15&7
        afr[m] = *(const short8*)&Ab[row * 64 + (((h * 4 + l4) ^ (l15 & 7)) * 8)];
      }
#pragma unroll
      for (int n = 0; n < NFRAG; ++n) {
        int row = ncol0 + n * 16 + l15;
        bfr[n] = *(const short8*)&Bb[row * 64 + (((h * 4 + l4) ^ (l15 & 7)) * 8)];
      }
      __builtin_amdgcn_s_setprio(1);
#pragma unroll
      for (int m = 0; m < MFRAG; ++m)
#pragma unroll
        for (int n = 0; n < NFRAG; ++n)
          acc[m][n] = __builtin_amdgcn_mfma_f32_16x16x32_bf16(afr[m], bfr[n], acc[m][n], 0, 0, 0);
      __builtin_amdgcn_s_setprio(0);
    }
    __builtin_amdgcn_sched_barrier(0);
  }

#pragma unroll
  for (int m = 0; m < MFRAG; ++m)
#pragma unroll
    for (int n = 0; n < NFRAG; ++n)
#pragma unroll
      for (int j = 0; j < 4; ++j) {
        int r = row0 + mrow0 + m * 16 + l4 * 4 + j;
        int cc = col0 + ncol0 + n * 16 + l15;
        if constexpr (BF16_OUT)
          ((unsigned short*)Cout)[(size_t)r * N + cc] = f2bf(acc[m][n][j]);
        else
          ((float*)Cout)[(size_t)r * N + cc] = acc[m][n][j];
      }
}

// ---------------- RoPE (in-place on fused QKV [2048][6144]) ----------------
__global__ __launch_bounds__(256) void rope_k(unsigned short* __restrict__ QKV) {
  int idx = blockIdx.x * blockDim.x + threadIdx.x;
  if (idx >= 2048 * 40 * 64) return;
  int j = idx & 63;
  int rest = idx >> 6;
  int slot = rest % 40;
  int s = rest / 40;
  int doff = (slot < 32) ? slot * 128 : 4096 + (slot - 32) * 128;
  unsigned short* p = QKV + (size_t)s * 6144 + doff;
  float inv = exp2f((float)j * -0.20762050593046015f);
  float ang = (float)s * inv;
  float sn, cs;
  sincosf(ang, &sn, &cs);
  float x1 = bf2f(p[j]), x2 = bf2f(p[j + 64]);
  p[j]      = f2bf(x1 * cs - x2 * sn);
  p[j + 64] = f2bf(x2 * cs + x1 * sn);
}

// ---------------- causal GQA flash attention (swapped QK^T, in-register softmax) ----------------
__global__ __launch_bounds__(512, 4) void attn_k(
    const unsigned short* __restrict__ QKV,  // [2048][6144]
    unsigned short* __restrict__ O) {        // [2048][4096]
  __shared__ unsigned short Ks[2][64 * 128];
  __shared__ unsigned short Vs[2][64 * 128];

  const int tid = threadIdx.x;
  const int wave = tid >> 6, lane = tid & 63;
  const int l15 = lane & 15, l4 = lane >> 4;

  const int bid = blockIdx.x;
  const int qt16 = bid & 15;
  const int h = (bid >> 4) & 31;
  const int qt = (h < 16) ? (15 - qt16) : qt16;
  const int hkv = h >> 2;
  const int q0 = qt * 128;
  const int qrow = q0 + wave * 16 + l15;
  const float C2 = 0.12751744219938793f;  // log2(e)/sqrt(128)

  const unsigned short* Qp = QKV + h * 128;
  const unsigned short* Kp = QKV + 4096 + hkv * 128;
  const unsigned short* Vp = QKV + 5120 + hkv * 128;

  const int vpr = tid >> 4;
  const int vd8 = tid & 15;
  const int vg8 = vpr >> 2, vjj = 2 * (vpr & 3);
  const int vn = vd8 >> 1, vch = (vd8 & 1) * 8;

  short8 qf[4];
#pragma unroll
  for (int kc = 0; kc < 4; ++kc)
    qf[kc] = *(const short8*)(Qp + (size_t)qrow * 6144 + kc * 32 + l4 * 8);

  f32x4 zv = {0.f, 0.f, 0.f, 0.f};
  f32x4 oacc[8];
#pragma unroll
  for (int n = 0; n < 8; ++n) oacc[n] = zv;
  float mrow = -3.0e38f, lrow = 0.f;

  auto stageK = [&](int kvn, int b) {
#pragma unroll
    for (int i = 0; i < 2; ++i) {
      int c = wave * 2 + i;
      int row = c * 4 + l4;
      int colel = (l15 * 8) ^ ((row & 7) << 3);
      gload_lds16(Kp + (size_t)(kvn + row) * 6144 + colel, &Ks[b][c * 512]);
    }
  };
  auto loadV = [&](int kvn, short8& va, short8& vb) {
    va = *(const short8*)(Vp + (size_t)(kvn + 2 * vpr) * 6144 + vd8 * 8);
    vb = *(const short8*)(Vp + (size_t)(kvn + 2 * vpr + 1) * 6144 + vd8 * 8);
  };
  auto writeV = [&](int b, const short8& va, const short8& vb) {
#pragma unroll
    for (int i = 0; i < 8; ++i) {
      int c = vch + i;
      unsigned int pack = (unsigned int)(unsigned short)va[i] |
                          ((unsigned int)(unsigned short)vb[i] << 16);
      *(unsigned int*)&Vs[b][vg8 * 1024 + vn * 128 + ((c ^ vn) & 15) * 8 + vjj] = pack;
    }
  };

  {
    short8 va, vb;
    stageK(0, 0);
    loadV(0, va, vb);
    writeV(0, va, vb);
  }
  __syncthreads();

  const int nt = 2 * qt + 2;
  for (int t = 0; t < nt; ++t) {
    const int cur = t & 1, nxt = cur ^ 1;
    const int kv0 = t * 64;
    const bool has_next = (t + 1 < nt);
    short8 va, vb;
    if (has_next) {
      stageK(kv0 + 64, nxt);
      loadV(kv0 + 64, va, vb);
    }

    // ---- swapped QK^T ----
    f32x4 sacc[4];
#pragma unroll
    for (int cb = 0; cb < 4; ++cb) sacc[cb] = zv;
    __builtin_amdgcn_s_setprio(1);
#pragma unroll
    for (int cb = 0; cb < 4; ++cb) {
      int row = cb * 16 + l15;
      int sw = (row & 7) << 3;
#pragma unroll
      for (int kc = 0; kc < 4; ++kc) {
        short8 kf = *(const short8*)&Ks[cur][row * 128 + ((kc * 32 + l4 * 8) ^ sw)];
        sacc[cb] = __builtin_amdgcn_mfma_f32_16x16x32_bf16(kf, qf[kc], sacc[cb], 0, 0, 0);
      }
    }
    __builtin_amdgcn_s_setprio(0);

    // ---- mask ----
    if (kv0 + 63 > q0 + wave * 16) {
#pragma unroll
      for (int cb = 0; cb < 4; ++cb)
#pragma unroll
        for (int j = 0; j < 4; ++j) {
          int kvpos = kv0 + cb * 16 + l4 * 4 + j;
          if (kvpos > qrow) sacc[cb][j] = -3.0e38f;
        }
    }

    // ---- row max ----
    float pm = sacc[0][0];
#pragma unroll
    for (int cb = 0; cb < 4; ++cb)
#pragma unroll
      for (int j = 0; j < 4; ++j) pm = fmaxf(pm, sacc[cb][j]);
    pm = fmaxf(pm, __shfl_xor(pm, 16, 64));
    pm = fmaxf(pm, __shfl_xor(pm, 32, 64));

    // ---- defer-max rescale ----
    if (__any(pm > mrow + 64.0f)) {
      float mn = fmaxf(mrow, pm);
      float rs = exp2f((mrow - mn) * C2);
      mrow = mn;
      lrow *= rs;
      float rs0 = __shfl(rs, 4 * l4 + 0, 64);
      float rs1 = __shfl(rs, 4 * l4 + 1, 64);
      float rs2 = __shfl(rs, 4 * l4 + 2, 64);
      float rs3 = __shfl(rs, 4 * l4 + 3, 64);
#pragma unroll
      for (int n = 0; n < 8; ++n) {
        oacc[n][0] *= rs0; oacc[n][1] *= rs1;
        oacc[n][2] *= rs2; oacc[n][3] *= rs3;
      }
    }

    // ---- p = exp2, sum, pack ----
    unsigned int pack[8];
    float psum = 0.f;
#pragma unroll
    for (int cb = 0; cb < 4; ++cb) {
      float p0 = exp2f((sacc[cb][0] - mrow) * C2);
      float p1 = exp2f((sacc[cb][1] - mrow) * C2);
      float p2 = exp2f((sacc[cb][2] - mrow) * C2);
      float p3 = exp2f((sacc[cb][3] - mrow) * C2);
      psum += (p0 + p1) + (p2 + p3);
      pack[cb * 2 + 0] = cvt_pk_bf16(p0, p1);
      pack[cb * 2 + 1] = cvt_pk_bf16(p2, p3);
    }
    lrow += psum;

    // ---- PV ----
#pragma unroll
    for (int ks = 0; ks < 2; ++ks) {
      u32x4 pw;
#pragma unroll
      for (int w = 0; w < 4; ++w) {
        int sl = l15 + 16 * ((2 * l4 + (w >> 1)) & 3);
        int v0 = __shfl((int)pack[4 * ks + (w & 1)], sl, 64);
        int v1 = __shfl((int)pack[4 * ks + 2 + (w & 1)], sl, 64);
        pw[w] = (lane < 32) ? (unsigned int)v0 : (unsigned int)v1;
      }
      short8 pf = __builtin_bit_cast(short8, pw);
      __builtin_amdgcn_s_setprio(1);
#pragma unroll
      for (int n = 0; n < 8; ++n) {
        short8 vf = *(const short8*)&Vs[cur][(ks * 4 + l4) * 1024 + n * 128 + ((l15 ^ n) & 15) * 8];
        oacc[n] = __builtin_amdgcn_mfma_f32_16x16x32_bf16(pf, vf, oacc[n], 0, 0, 0);
      }
      __builtin_amdgcn_s_setprio(0);
    }

    if (has_next) writeV(nxt, va, vb);
    __syncthreads();
  }

  // ---- epilogue ----
  lrow += __shfl_xor(lrow, 16, 64);
  lrow += __shfl_xor(lrow, 32, 64);
  float linv = 1.0f / lrow;
  float li0 = __shfl(linv, 4 * l4 + 0, 64);
  float li1 = __shfl(linv, 4 * l4 + 1, 64);
  float li2 = __shfl(linv, 4 * l4 + 2, 64);
  float li3 = __shfl(linv, 4 * l4 + 3, 64);
#pragma unroll
  for (int n = 0; n < 8; ++n) {
    int r = q0 + wave * 16 + l4 * 4;
    size_t base = (size_t)r * 4096 + h * 128 + n * 16 + l15;
    O[base]          = f2bf_fast(oacc[n][0] * li0);
    O[base + 4096]   = f2bf_fast(oacc[n][1] * li1);
    O[base + 8192]   = f2bf_fast(oacc[n][2] * li2);
    O[base + 12288]  = f2bf_fast(oacc[n][3] * li3);
  }
}

extern "C" void kernel_launch(void* const* d_in, const int* in_sizes, int n_in,
                              void* d_out, int out_size, void* d_ws, size_t ws_size,
                              hipStream_t stream) {
  const float* hid = (const float*)d_in[0];
  const float* Wq  = (const float*)d_in[1];
  const float* Wk  = (const float*)d_in[2];
  const float* Wv  = (const float*)d_in[3];
  const float* Wo  = (const float*)d_in[4];

  char* ws = (char*)d_ws;
  size_t off = 0;
  unsigned short* hid_b = (unsigned short*)(ws + off); off += (size_t)2048 * 4096 * 2;
  unsigned short* Wq_b  = (unsigned short*)(ws + off); off += (size_t)4096 * 4096 * 2;
  unsigned short* Wk_b  = (unsigned short*)(ws + off); off += (size_t)1024 * 4096 * 2;
  unsigned short* Wv_b  = (unsigned short*)(ws + off); off += (size_t)1024 * 4096 * 2;
  unsigned short* Wo_b  = (unsigned short*)(ws + off); off += (size_t)4096 * 4096 * 2;
  unsigned short* QKV   = (unsigned short*)(ws + off); off += (size_t)2048 * 6144 * 2;
  unsigned short* Ob    = (unsigned short*)(ws + off); off += (size_t)2048 * 4096 * 2;
  (void)Wk_b; (void)Wv_b;

  cvt_all<<<4096, 256, 0, stream>>>(hid, Wq, Wk, Wv, Wo, hid_b);

  // fused QKV projection: B = [Wq; Wk; Wv] contiguous, N = 6144
  // grid 32x16 = 512 blocks = 2/CU (80KB LDS each), BK=64 double-buffered
  gemm_p2<128, 192, true><<<dim3(32, 16), 256, 0, stream>>>(hid_b, Wq_b, (void*)QKV, 2048, 6144, 4096);

  rope_k<<<20480, 256, 0, stream>>>(QKV);

  attn_k<<<512, 512, 0, stream>>>(QKV, Ob);

  // O projection: grid 32x16 = 512 blocks = 2/CU (64KB LDS each)
  gemm_p2<128, 128, false><<<dim3(32, 16), 256, 0, stream>>>(Ob, Wo_b, d_out, 2048, 4096, 4096);
}